// Round 9
// baseline (2362.510 us; speedup 1.0000x reference)
//
#include <hip/hip_runtime.h>
#include <hip/hip_bf16.h>

// ---------------------------------------------------------------------------
// 2-layer LSTM, B=64 T=256 N=512 H=1024.
// R9: chunked dataflow. h0's K=1024 is consumed in 8 chunks of 128 units,
// each gated on the 16 producing WGs' flags (per-chunk subset poll by every
// wave) and software-pipelined (load ch+1 while MFMA ch). Early h0 publish +
// split flags (f0 after h0 drain, f1 after h1 drain) keep layer1 work off the
// h0 recurrence chain. Write-once rings, cached consumer loads, uncached
// publishes. Weights pinned in VGPRs.
// ---------------------------------------------------------------------------

#define T_ 256
#define B_ 64
#define N_ 512
#define H_ 1024
#define FH_ 4096
#define NWG_SEQ 256
#define BH_ (B_ * H_)

typedef _Float16 f16;
typedef _Float16 f16x4 __attribute__((ext_vector_type(4)));
typedef _Float16 f16x8 __attribute__((ext_vector_type(8)));
typedef float f32x4 __attribute__((ext_vector_type(4)));
typedef unsigned long long ull;

template <bool V> struct BC { static constexpr bool value = V; };

__device__ __forceinline__ float sigf(float x) { return 1.f / (1.f + __expf(-x)); }
__device__ __forceinline__ float tanhf_fast(float x) { return 1.f - 2.f / (__expf(2.f * x) + 1.f); }

// uncached (bypass L1/L2, MALL-coherent) accessors
__device__ __forceinline__ void st_u64g(ull* p, ull v) {
  __hip_atomic_store(p, v, __ATOMIC_RELAXED, __HIP_MEMORY_SCOPE_AGENT);
}
__device__ __forceinline__ void st_u32g(unsigned* p, unsigned v) {
  __hip_atomic_store(p, v, __ATOMIC_RELAXED, __HIP_MEMORY_SCOPE_AGENT);
}
__device__ __forceinline__ ull ld_u64g(const ull* p) {
  return __hip_atomic_load(p, __ATOMIC_RELAXED, __HIP_MEMORY_SCOPE_AGENT);
}
__device__ __forceinline__ f16x8 ld_b128_nc(const f16* p) {
  f16x8 r;
  asm volatile("global_load_dwordx4 %0, %1, off sc0 sc1" : "=v"(r) : "v"(p));
  return r;
}

// ---------------------------------------------------------------------------
// init / convert kernel
// ---------------------------------------------------------------------------
__global__ __launch_bounds__(256) void init_all(
    const float* __restrict__ x, const float* __restrict__ h,
    const float* __restrict__ Wih0, const float* __restrict__ bih0, const float* __restrict__ bhh0,
    const float* __restrict__ Whh0, const float* __restrict__ Wih1, const float* __restrict__ Whh1,
    const float* __restrict__ bih1, const float* __restrict__ bhh1,
    f16* __restrict__ xT, f16* __restrict__ wih0, f16* __restrict__ whh0,
    f16* __restrict__ wih1, f16* __restrict__ whh1,
    float* __restrict__ bias0, float* __restrict__ bias1,
    f16* __restrict__ hinit, unsigned* __restrict__ flags)
{
  const int stride = gridDim.x * blockDim.x;
  const int t0 = blockIdx.x * blockDim.x + threadIdx.x;

  for (int i = t0; i < T_ * B_ * N_; i += stride) {
    int n = i & (N_ - 1);
    int tb = i >> 9;
    int b = tb & (B_ - 1);
    int t = tb >> 6;
    xT[i] = (f16)x[((size_t)b * T_ + t) * N_ + n];
  }
  for (int i = t0; i < FH_ * N_; i += stride) wih0[i] = (f16)Wih0[i];
  for (int i = t0; i < FH_ * H_; i += stride) {
    whh0[i] = (f16)Whh0[i];
    wih1[i] = (f16)Wih1[i];
    whh1[i] = (f16)Whh1[i];
  }
  for (int i = t0; i < FH_; i += stride) {
    bias0[i] = bih0[i] + bhh0[i];
    bias1[i] = bih1[i] + bhh1[i];
  }
  for (int i = t0; i < 2 * BH_; i += stride) hinit[i] = (f16)h[i];
  if (t0 < 512) flags[t0] = 0u;
}

// ---------------------------------------------------------------------------
// GEMM: pre0T[t][col][b] = (xT @ wih0^T + bias0), stored f16 TRANSPOSED.
// ---------------------------------------------------------------------------
__global__ __launch_bounds__(256) void gemm_pre0(
    const f16* __restrict__ xT, const f16* __restrict__ wih0,
    const float* __restrict__ bias0, f16* __restrict__ pre0T)
{
  const int wid = threadIdx.x >> 6;
  const int lane = threadIdx.x & 63;
  const int lr = lane & 15;
  const int lkq = (lane >> 4) << 3;
  const int lrq = (lane >> 4) << 2;

  const int mt = blockIdx.x & 255;
  const int ct = (blockIdx.x >> 8) * 4 + wid;
  const int row0 = mt * 64, col0 = ct * 64;

  f32x4 acc[4][4] = {};
  const f16* Abase = xT + (size_t)row0 * N_;

  #pragma unroll 2
  for (int kk = 0; kk < N_ / 32; ++kk) {
    const int k = kk * 32 + lkq;
    f16x8 a[4], b[4];
    #pragma unroll
    for (int r = 0; r < 4; ++r)
      a[r] = *(const f16x8*)(Abase + (size_t)(r * 16 + lr) * N_ + k);
    #pragma unroll
    for (int cf = 0; cf < 4; ++cf)
      b[cf] = *(const f16x8*)(wih0 + (size_t)(col0 + cf * 16 + lr) * N_ + k);
    #pragma unroll
    for (int r = 0; r < 4; ++r)
      #pragma unroll
      for (int cf = 0; cf < 4; ++cf)
        acc[r][cf] = __builtin_amdgcn_mfma_f32_16x16x32_f16(a[r], b[cf], acc[r][cf], 0, 0, 0);
  }

  #pragma unroll
  for (int r = 0; r < 4; ++r) {
    #pragma unroll
    for (int cf = 0; cf < 4; ++cf) {
      const int col = col0 + cf * 16 + lr;
      const float bv = bias0[col];
      f16x4 pv;
      #pragma unroll
      for (int ri = 0; ri < 4; ++ri) pv[ri] = (f16)(acc[r][cf][ri] + bv);
      *(f16x4*)(pre0T + ((size_t)mt * FH_ + col) * 64 + r * 16 + lrq) = pv;
    }
  }
}

// ---------------------------------------------------------------------------
// Persistent chunked-dataflow kernel. 256 WGs x 256 threads (1 WG/CU).
// Pod P = 128 WGs, batch rows P*32..P*32+31. WG owns 8 units of each gate.
// Epoch e: layer0 step e (publish h0 + f0 EARLY), layer1 step e-1 (f1 late).
// f0 = flags + pod*128, f1 = flags + 256 + pod*128. Value = epochs done + 1.
// Chunk ch (128 units) of h vectors is produced by WG slots 16ch..16ch+15.
// ---------------------------------------------------------------------------
template <bool DEEP>
__global__ __launch_bounds__(256, 1) void lstm_seq(
    const f16* __restrict__ pre0T, const f16* __restrict__ whh0,
    const f16* __restrict__ wih1, const f16* __restrict__ whh1,
    const float* __restrict__ bias1, const f16* __restrict__ hinit,
    const float* __restrict__ cin,
    f16* __restrict__ h0r, f16* __restrict__ h1r,
    float* __restrict__ out, unsigned* __restrict__ flags)
{
  __shared__ __align__(16) float exc[2][4][32][33];   // partial-sum exchange
  __shared__ __align__(16) f16 smH[2][32][8];         // packed h outputs

  const int tid = threadIdx.x;
  const int p = tid >> 6;          // wave = K-quarter (within each chunk)
  const int lane = tid & 63;
  const int lr = lane & 15;
  const int lq = lane >> 4;
  const int lkq = lq << 3;
  const int lrq = lq << 2;

  const int wg = blockIdx.x;
  const int pod = wg >> 7;
  const int slot = wg & 127;
  const int rs = pod << 5;
  const int ub = slot << 3;        // unit base: 8 units per gate
  unsigned* f0p = flags + (pod << 7);
  unsigned* f1p = flags + 256 + (pod << 7);

  auto rt = [&](int t) -> size_t { return DEEP ? (size_t)t : (size_t)(t & 7); };

  // ---- preload weight fragments (chunk-mapped k) ----
  f16x8 l0w[2][8], l1aw[2][8], l1bw[2][8];
  #pragma unroll
  for (int cf = 0; cf < 2; ++cf) {
    const size_t wr = (size_t)((2 * cf + (lr >> 3)) * H_ + ub + (lr & 7)) * H_;
    #pragma unroll
    for (int ch = 0; ch < 8; ++ch) {
      const int k = ch * 128 + p * 32 + lkq;
      l0w[cf][ch]  = *(const f16x8*)(whh0 + wr + k);
      l1aw[cf][ch] = *(const f16x8*)(wih1 + wr + k);
      l1bw[cf][ch] = *(const f16x8*)(whh1 + wr + k);
    }
  }

  // ---- per-thread cell state ----
  const int crow = tid & 31;
  const int cu = tid >> 5;
  const size_t cell = (size_t)(rs + crow) * H_ + ub + cu;
  float c0 = cin[cell];
  float c1 = cin[(size_t)BH_ + cell];
  float b1v[4];
  #pragma unroll
  for (int g = 0; g < 4; ++g) b1v[g] = bias1[g * H_ + ub + cu];

  float* outh = out + (size_t)B_ * T_ * H_;
  float* outc = outh + 2 * BH_;

  // per-chunk subset poll on f0 (executed independently by every wave)
  auto wchunk = [&](int ch, unsigned tgt) {
    if (tgt == 0u) return;
    const ull* fp = (const ull*)f0p;
    const int idx = 8 * ch + (lane & 7);
    for (;;) {
      ull v = ld_u64g(&fp[idx]);
      const bool ok = ((unsigned)v >= tgt) && ((unsigned)(v >> 32) >= tgt);
      if (__ballot(ok) == ~0ull) break;
      __builtin_amdgcn_s_sleep(1);
    }
    asm volatile("" ::: "memory");
  };
  auto waitwide = [&](const unsigned* base, unsigned tgt) {
    const ull* fp = (const ull*)base;
    for (;;) {
      ull v = ld_u64g(&fp[lane]);
      const bool ok = ((unsigned)v >= tgt) && ((unsigned)(v >> 32) >= tgt);
      if (__ballot(ok) == ~0ull) break;
      __builtin_amdgcn_s_sleep(1);
    }
    asm volatile("" ::: "memory");
  };

  auto body = [&](auto A0c, auto A1c, int e) {
    constexpr bool A0 = decltype(A0c)::value;
    constexpr bool A1 = decltype(A1c)::value;

    // pre0 additive term (cached, ungated)
    float pf[4];
    if (A0) {
      #pragma unroll
      for (int g = 0; g < 4; ++g)
        pf[g] = (float)pre0T[((size_t)e * FH_ + g * H_ + ub + cu) * 64 + rs + crow];
    }

    if (!DEEP && e >= 7) waitwide(f1p, (unsigned)(e - 6));  // ring-reuse guard

    const f16* h0s = ((e == 0) ? hinit : h0r + rt(e - 1) * BH_) + (size_t)rs * H_;

    f32x4 acc0[2][2] = {};
    f32x4 acc1[2][2] = {};

    if constexpr (DEEP) {
      // ---- chunk-gated, software-pipelined h0 consumption ----
      f16x8 ca0, ca1, pa0, pa1;
      wchunk(0, (unsigned)e);
      ca0 = *(const f16x8*)(h0s + (size_t)lr * H_ + (p * 32 + lkq));
      ca1 = *(const f16x8*)(h0s + (size_t)(16 + lr) * H_ + (p * 32 + lkq));
      #pragma unroll
      for (int ch = 0; ch < 8; ++ch) {
        if (ch < 7) {
          wchunk(ch + 1, (unsigned)e);
          const int k = (ch + 1) * 128 + p * 32 + lkq;
          pa0 = *(const f16x8*)(h0s + (size_t)lr * H_ + k);
          pa1 = *(const f16x8*)(h0s + (size_t)(16 + lr) * H_ + k);
        }
        if (A0) {
          #pragma unroll
          for (int cf = 0; cf < 2; ++cf) {
            acc0[cf][0] = __builtin_amdgcn_mfma_f32_16x16x32_f16(ca0, l0w[cf][ch], acc0[cf][0], 0, 0, 0);
            acc0[cf][1] = __builtin_amdgcn_mfma_f32_16x16x32_f16(ca1, l0w[cf][ch], acc0[cf][1], 0, 0, 0);
          }
        }
        if (A1) {
          #pragma unroll
          for (int cf = 0; cf < 2; ++cf) {
            acc1[cf][0] = __builtin_amdgcn_mfma_f32_16x16x32_f16(ca0, l1aw[cf][ch], acc1[cf][0], 0, 0, 0);
            acc1[cf][1] = __builtin_amdgcn_mfma_f32_16x16x32_f16(ca1, l1aw[cf][ch], acc1[cf][1], 0, 0, 0);
          }
        }
        if (ch < 7) { ca0 = pa0; ca1 = pa1; }
      }
    } else {
      // ---- shallow fallback: bulk gate + uncached loads ----
      if (e > 0) waitwide(f0p, (unsigned)e);
      f16x8 a0v[8], a1v[8];
      #pragma unroll
      for (int ch = 0; ch < 8; ++ch) {
        const int k = ch * 128 + p * 32 + lkq;
        a0v[ch] = ld_b128_nc(h0s + (size_t)lr * H_ + k);
        a1v[ch] = ld_b128_nc(h0s + (size_t)(16 + lr) * H_ + k);
      }
      asm volatile("s_waitcnt vmcnt(0)" ::: "memory");
      __builtin_amdgcn_sched_barrier(0);
      #pragma unroll
      for (int ch = 0; ch < 8; ++ch) {
        if (A0) {
          #pragma unroll
          for (int cf = 0; cf < 2; ++cf) {
            acc0[cf][0] = __builtin_amdgcn_mfma_f32_16x16x32_f16(a0v[ch], l0w[cf][ch], acc0[cf][0], 0, 0, 0);
            acc0[cf][1] = __builtin_amdgcn_mfma_f32_16x16x32_f16(a1v[ch], l0w[cf][ch], acc0[cf][1], 0, 0, 0);
          }
        }
        if (A1) {
          #pragma unroll
          for (int cf = 0; cf < 2; ++cf) {
            acc1[cf][0] = __builtin_amdgcn_mfma_f32_16x16x32_f16(a0v[ch], l1aw[cf][ch], acc1[cf][0], 0, 0, 0);
            acc1[cf][1] = __builtin_amdgcn_mfma_f32_16x16x32_f16(a1v[ch], l1aw[cf][ch], acc1[cf][1], 0, 0, 0);
          }
        }
      }
    }

    // ---- L0 exchange -> update -> EARLY publish + f0 ----
    if (A0) {
      #pragma unroll
      for (int cf = 0; cf < 2; ++cf)
        #pragma unroll
        for (int rf = 0; rf < 2; ++rf)
          #pragma unroll
          for (int ri = 0; ri < 4; ++ri)
            exc[0][p][rf * 16 + lrq + ri][cf * 16 + lr] = acc0[cf][rf][ri];
    }
    __syncthreads();   // B1

    float hn0 = 0.f, cn0 = 0.f;
    if (A0) {
      float gv[4];
      #pragma unroll
      for (int g = 0; g < 4; ++g)
        gv[g] = exc[0][0][crow][g * 8 + cu] + exc[0][1][crow][g * 8 + cu]
              + exc[0][2][crow][g * 8 + cu] + exc[0][3][crow][g * 8 + cu] + pf[g];
      cn0 = sigf(gv[1]) * c0 + sigf(gv[0]) * tanhf_fast(gv[2]);
      hn0 = sigf(gv[3]) * tanhf_fast(cn0);
      c0 = cn0;
      smH[0][crow][cu] = (f16)hn0;
    }
    __syncthreads();   // B2

    if (A0 && p == 0) {
      const int row = lane >> 1, half = lane & 1;
      ull v = *(const ull*)&smH[0][row][half * 4];
      st_u64g((ull*)(h0r + rt(e) * BH_ + (size_t)(rs + row) * H_ + ub + half * 4), v);
      asm volatile("s_waitcnt vmcnt(0)" ::: "memory");
      if (lane == 0) st_u32g(&f0p[slot], (unsigned)(e + 1));
    }

    // ---- L1: h1 gate (slack), loads, MFMAs, exchange ----
    if (A1) {
      if (e >= 2) waitwide(f1p, (unsigned)e);
      const f16* h1s = ((e == 1) ? hinit + BH_ : h1r + rt(e - 2) * BH_) + (size_t)rs * H_;
      f16x8 c0v[8], c1v[8];
      #pragma unroll
      for (int ch = 0; ch < 8; ++ch) {
        const int k = ch * 128 + p * 32 + lkq;
        if constexpr (DEEP) {
          c0v[ch] = *(const f16x8*)(h1s + (size_t)lr * H_ + k);
          c1v[ch] = *(const f16x8*)(h1s + (size_t)(16 + lr) * H_ + k);
        } else {
          c0v[ch] = ld_b128_nc(h1s + (size_t)lr * H_ + k);
          c1v[ch] = ld_b128_nc(h1s + (size_t)(16 + lr) * H_ + k);
        }
      }
      if (!DEEP) {
        asm volatile("s_waitcnt vmcnt(0)" ::: "memory");
        __builtin_amdgcn_sched_barrier(0);
      }
      #pragma unroll
      for (int ch = 0; ch < 8; ++ch) {
        #pragma unroll
        for (int cf = 0; cf < 2; ++cf) {
          acc1[cf][0] = __builtin_amdgcn_mfma_f32_16x16x32_f16(c0v[ch], l1bw[cf][ch], acc1[cf][0], 0, 0, 0);
          acc1[cf][1] = __builtin_amdgcn_mfma_f32_16x16x32_f16(c1v[ch], l1bw[cf][ch], acc1[cf][1], 0, 0, 0);
        }
      }
      #pragma unroll
      for (int cf = 0; cf < 2; ++cf)
        #pragma unroll
        for (int rf = 0; rf < 2; ++rf)
          #pragma unroll
          for (int ri = 0; ri < 4; ++ri)
            exc[1][p][rf * 16 + lrq + ri][cf * 16 + lr] = acc1[cf][rf][ri];
    }
    __syncthreads();   // B3

    float hn1 = 0.f, cn1 = 0.f;
    if (A1) {
      float gv[4];
      #pragma unroll
      for (int g = 0; g < 4; ++g)
        gv[g] = exc[1][0][crow][g * 8 + cu] + exc[1][1][crow][g * 8 + cu]
              + exc[1][2][crow][g * 8 + cu] + exc[1][3][crow][g * 8 + cu] + b1v[g];
      cn1 = sigf(gv[1]) * c1 + sigf(gv[0]) * tanhf_fast(gv[2]);
      hn1 = sigf(gv[3]) * tanhf_fast(cn1);
      c1 = cn1;
      smH[1][crow][cu] = (f16)hn1;
    }
    __syncthreads();   // B4

    if (A1 && p == 1) {
      const int row = lane >> 1, half = lane & 1;
      ull v = *(const ull*)&smH[1][row][half * 4];
      st_u64g((ull*)(h1r + rt(e - 1) * BH_ + (size_t)(rs + row) * H_ + ub + half * 4), v);
      asm volatile("s_waitcnt vmcnt(0)" ::: "memory");
      if (lane == 0) st_u32g(&f1p[slot], (unsigned)(e + 1));
    }

    // ---- off-critical-path cached outputs ----
    if (A0 && e == T_ - 1) { outh[cell] = hn0; outc[cell] = cn0; }
    if (A1) {
      out[(size_t)(rs + crow) * (T_ * H_) + (size_t)(e - 1) * H_ + ub + cu] = hn1;
      if (e == T_) { outh[BH_ + cell] = hn1; outc[BH_ + cell] = cn1; }
    }
  };

  body(BC<true>{}, BC<false>{}, 0);
  for (int e = 1; e < T_; ++e) body(BC<true>{}, BC<true>{}, e);
  body(BC<false>{}, BC<true>{}, T_);
}

// ---------------------------------------------------------------------------
extern "C" void kernel_launch(void* const* d_in, const int* in_sizes, int n_in,
                              void* d_out, int out_size, void* d_ws, size_t ws_size,
                              hipStream_t stream)
{
  const float* x    = (const float*)d_in[0];
  const float* h    = (const float*)d_in[1];
  const float* c    = (const float*)d_in[2];
  const float* Wih0 = (const float*)d_in[3];
  const float* Whh0 = (const float*)d_in[4];
  const float* bih0 = (const float*)d_in[5];
  const float* bhh0 = (const float*)d_in[6];
  const float* Wih1 = (const float*)d_in[7];
  const float* Whh1 = (const float*)d_in[8];
  const float* bih1 = (const float*)d_in[9];
  const float* bhh1 = (const float*)d_in[10];

  char* w = (char*)d_ws;
  size_t off = 0;
  auto carve = [&](size_t bytes) -> char* {
    char* ptr = w + off;
    off = (off + bytes + 255) & ~(size_t)255;
    return ptr;
  };
  f16*   pre0T = (f16*)  carve((size_t)T_ * B_ * FH_ * 2);
  f16*   xT    = (f16*)  carve((size_t)T_ * B_ * N_ * 2);
  f16*   wih0  = (f16*)  carve((size_t)FH_ * N_ * 2);
  f16*   whh0  = (f16*)  carve((size_t)FH_ * H_ * 2);
  f16*   wih1  = (f16*)  carve((size_t)FH_ * H_ * 2);
  f16*   whh1  = (f16*)  carve((size_t)FH_ * H_ * 2);
  float* bias0 = (float*)carve((size_t)FH_ * 4);
  float* bias1 = (float*)carve((size_t)FH_ * 4);
  f16*   hinit = (f16*)  carve((size_t)2 * BH_ * 2);
  f16*   h0s   = (f16*)  carve((size_t)8 * BH_ * 2);   // shallow fallback rings
  f16*   h1s   = (f16*)  carve((size_t)8 * BH_ * 2);
  unsigned* flags = (unsigned*)carve(512 * 4);
  const size_t base_end = off;
  f16*   h0ring = (f16*) carve((size_t)T_ * BH_ * 2);  // deep write-once rings
  f16*   h1ring = (f16*) carve((size_t)T_ * BH_ * 2);
  const bool deep = (off <= ws_size);
  if (base_end > ws_size) return;

  init_all<<<2048, 256, 0, stream>>>(x, h, Wih0, bih0, bhh0, Whh0, Wih1, Whh1, bih1, bhh1,
                                     xT, wih0, whh0, wih1, whh1, bias0, bias1, hinit, flags);
  gemm_pre0<<<4096, 256, 0, stream>>>(xT, wih0, bias0, pre0T);
  if (deep)
    lstm_seq<true><<<NWG_SEQ, 256, 0, stream>>>(pre0T, whh0, wih1, whh1, bias1, hinit,
                                                (const float*)c, h0ring, h1ring,
                                                (float*)d_out, flags);
  else
    lstm_seq<false><<<NWG_SEQ, 256, 0, stream>>>(pre0T, whh0, wih1, whh1, bias1, hinit,
                                                 (const float*)c, h0s, h1s,
                                                 (float*)d_out, flags);
}

// Round 10
// 1944.403 us; speedup vs baseline: 1.2150x; 1.2150x over previous
//
#include <hip/hip_runtime.h>
#include <hip/hip_bf16.h>

// ---------------------------------------------------------------------------
// 2-layer LSTM, B=64 T=256 N=512 H=1024.
// R10: R6 structure (split phases, EARLY h0 publish, cached write-once rings)
// + per-WG flag STORES (no atomicAdd fan-in; wave0 wide-poll, one u64 load
// per lane per iteration) + wih1 MFMAs deferred to phase 2 (a-frags stay in
// registers). One publish->drain->flag->poll->load hop on the h0 recurrence.
// ---------------------------------------------------------------------------

#define T_ 256
#define B_ 64
#define N_ 512
#define H_ 1024
#define FH_ 4096
#define NWG_SEQ 256
#define BH_ (B_ * H_)

typedef _Float16 f16;
typedef _Float16 f16x4 __attribute__((ext_vector_type(4)));
typedef _Float16 f16x8 __attribute__((ext_vector_type(8)));
typedef float f32x4 __attribute__((ext_vector_type(4)));
typedef unsigned long long ull;

template <bool V> struct BC { static constexpr bool value = V; };

__device__ __forceinline__ float sigf(float x) { return 1.f / (1.f + __expf(-x)); }
__device__ __forceinline__ float tanhf_fast(float x) { return 1.f - 2.f / (__expf(2.f * x) + 1.f); }

// uncached (bypass L1/L2, MALL-coherent) accessors
__device__ __forceinline__ void st_u64g(ull* p, ull v) {
  __hip_atomic_store(p, v, __ATOMIC_RELAXED, __HIP_MEMORY_SCOPE_AGENT);
}
__device__ __forceinline__ void st_u32g(unsigned* p, unsigned v) {
  __hip_atomic_store(p, v, __ATOMIC_RELAXED, __HIP_MEMORY_SCOPE_AGENT);
}
__device__ __forceinline__ ull ld_u64g(const ull* p) {
  return __hip_atomic_load(p, __ATOMIC_RELAXED, __HIP_MEMORY_SCOPE_AGENT);
}
__device__ __forceinline__ f16x8 ld_b128_nc(const f16* p) {
  f16x8 r;
  asm volatile("global_load_dwordx4 %0, %1, off sc0 sc1" : "=v"(r) : "v"(p));
  return r;
}

// ---------------------------------------------------------------------------
// init / convert kernel
// ---------------------------------------------------------------------------
__global__ __launch_bounds__(256) void init_all(
    const float* __restrict__ x, const float* __restrict__ h,
    const float* __restrict__ Wih0, const float* __restrict__ bih0, const float* __restrict__ bhh0,
    const float* __restrict__ Whh0, const float* __restrict__ Wih1, const float* __restrict__ Whh1,
    const float* __restrict__ bih1, const float* __restrict__ bhh1,
    f16* __restrict__ xT, f16* __restrict__ wih0, f16* __restrict__ whh0,
    f16* __restrict__ wih1, f16* __restrict__ whh1,
    float* __restrict__ bias0, float* __restrict__ bias1,
    f16* __restrict__ hinit, unsigned* __restrict__ flags)
{
  const int stride = gridDim.x * blockDim.x;
  const int t0 = blockIdx.x * blockDim.x + threadIdx.x;

  for (int i = t0; i < T_ * B_ * N_; i += stride) {
    int n = i & (N_ - 1);
    int tb = i >> 9;
    int b = tb & (B_ - 1);
    int t = tb >> 6;
    xT[i] = (f16)x[((size_t)b * T_ + t) * N_ + n];
  }
  for (int i = t0; i < FH_ * N_; i += stride) wih0[i] = (f16)Wih0[i];
  for (int i = t0; i < FH_ * H_; i += stride) {
    whh0[i] = (f16)Whh0[i];
    wih1[i] = (f16)Wih1[i];
    whh1[i] = (f16)Whh1[i];
  }
  for (int i = t0; i < FH_; i += stride) {
    bias0[i] = bih0[i] + bhh0[i];
    bias1[i] = bih1[i] + bhh1[i];
  }
  for (int i = t0; i < 2 * BH_; i += stride) hinit[i] = (f16)h[i];
  if (t0 < 512) flags[t0] = 0u;
}

// ---------------------------------------------------------------------------
// GEMM: pre0T[t][col][b] = (xT @ wih0^T + bias0), stored f16 TRANSPOSED.
// ---------------------------------------------------------------------------
__global__ __launch_bounds__(256) void gemm_pre0(
    const f16* __restrict__ xT, const f16* __restrict__ wih0,
    const float* __restrict__ bias0, f16* __restrict__ pre0T)
{
  const int wid = threadIdx.x >> 6;
  const int lane = threadIdx.x & 63;
  const int lr = lane & 15;
  const int lkq = (lane >> 4) << 3;
  const int lrq = (lane >> 4) << 2;

  const int mt = blockIdx.x & 255;
  const int ct = (blockIdx.x >> 8) * 4 + wid;
  const int row0 = mt * 64, col0 = ct * 64;

  f32x4 acc[4][4] = {};
  const f16* Abase = xT + (size_t)row0 * N_;

  #pragma unroll 2
  for (int kk = 0; kk < N_ / 32; ++kk) {
    const int k = kk * 32 + lkq;
    f16x8 a[4], b[4];
    #pragma unroll
    for (int r = 0; r < 4; ++r)
      a[r] = *(const f16x8*)(Abase + (size_t)(r * 16 + lr) * N_ + k);
    #pragma unroll
    for (int cf = 0; cf < 4; ++cf)
      b[cf] = *(const f16x8*)(wih0 + (size_t)(col0 + cf * 16 + lr) * N_ + k);
    #pragma unroll
    for (int r = 0; r < 4; ++r)
      #pragma unroll
      for (int cf = 0; cf < 4; ++cf)
        acc[r][cf] = __builtin_amdgcn_mfma_f32_16x16x32_f16(a[r], b[cf], acc[r][cf], 0, 0, 0);
  }

  #pragma unroll
  for (int r = 0; r < 4; ++r) {
    #pragma unroll
    for (int cf = 0; cf < 4; ++cf) {
      const int col = col0 + cf * 16 + lr;
      const float bv = bias0[col];
      f16x4 pv;
      #pragma unroll
      for (int ri = 0; ri < 4; ++ri) pv[ri] = (f16)(acc[r][cf][ri] + bv);
      *(f16x4*)(pre0T + ((size_t)mt * FH_ + col) * 64 + r * 16 + lrq) = pv;
    }
  }
}

// ---------------------------------------------------------------------------
// Persistent dataflow kernel. 256 WGs x 256 threads (1 WG/CU).
// Pod P = 128 WGs, batch rows P*32..P*32+31. WG owns 8 units of each gate.
// Epoch e: phase1 = layer0 step e (publish h0 + f0 EARLY);
//          phase2 = layer1 step e-1 (wih1 on live a-frags, whh1 on h1).
// f0 = flags + pod*128, f1 = flags + 256 + pod*128; value = epochs done + 1.
// ---------------------------------------------------------------------------
template <bool DEEP>
__global__ __launch_bounds__(256, 1) void lstm_seq(
    const f16* __restrict__ pre0T, const f16* __restrict__ whh0,
    const f16* __restrict__ wih1, const f16* __restrict__ whh1,
    const float* __restrict__ bias1, const f16* __restrict__ hinit,
    const float* __restrict__ cin,
    f16* __restrict__ h0r, f16* __restrict__ h1r,
    float* __restrict__ out, unsigned* __restrict__ flags)
{
  __shared__ __align__(16) float exc[2][4][32][33];   // partial-sum exchange
  __shared__ __align__(16) f16 smH[2][32][8];         // packed h outputs

  const int tid = threadIdx.x;
  const int p = tid >> 6;          // wave = K-quarter
  const int lane = tid & 63;
  const int lr = lane & 15;
  const int lq = lane >> 4;
  const int lkq = lq << 3;
  const int lrq = lq << 2;

  const int wg = blockIdx.x;
  const int pod = wg >> 7;
  const int slot = wg & 127;
  const int rs = pod << 5;
  const int ub = slot << 3;        // unit base: 8 units per gate
  unsigned* f0p = flags + (pod << 7);
  unsigned* f1p = flags + 256 + (pod << 7);

  auto rt = [&](int t) -> size_t { return DEEP ? (size_t)t : (size_t)(t & 7); };

  // ---- preload weight fragments (48 x f16x8) ----
  f16x8 l0w[2][8], l1aw[2][8], l1bw[2][8];
  #pragma unroll
  for (int cf = 0; cf < 2; ++cf) {
    const size_t wr = (size_t)((2 * cf + (lr >> 3)) * H_ + ub + (lr & 7)) * H_;
    #pragma unroll
    for (int j = 0; j < 8; ++j) {
      const int k = (p * 8 + j) * 32 + lkq;
      l0w[cf][j]  = *(const f16x8*)(whh0 + wr + k);
      l1aw[cf][j] = *(const f16x8*)(wih1 + wr + k);
      l1bw[cf][j] = *(const f16x8*)(whh1 + wr + k);
    }
  }

  // ---- per-thread cell state ----
  const int crow = tid & 31;
  const int cu = tid >> 5;
  const size_t cell = (size_t)(rs + crow) * H_ + ub + cu;
  float c0 = cin[cell];
  float c1 = cin[(size_t)BH_ + cell];
  float b1v[4];
  #pragma unroll
  for (int g = 0; g < 4; ++g) b1v[g] = bias1[g * H_ + ub + cu];

  float* outh = out + (size_t)B_ * T_ * H_;
  float* outc = outh + 2 * BH_;

  // wide poll: lane i checks flags 2i, 2i+1; call from wave0 only
  auto waitwide = [&](const unsigned* base, unsigned tgt) {
    const ull* fp = (const ull*)base;
    for (;;) {
      ull v = ld_u64g(&fp[lane]);
      const bool ok = ((unsigned)v >= tgt) && ((unsigned)(v >> 32) >= tgt);
      if (__ballot(ok) == ~0ull) break;
      __builtin_amdgcn_s_sleep(1);
    }
    asm volatile("" ::: "memory");
  };

  auto body = [&](auto A0c, auto A1c, int e) {
    constexpr bool A0 = decltype(A0c)::value;
    constexpr bool A1 = decltype(A1c)::value;

    // pre0 additive term (cached, issued before the gate)
    float pf[4];
    if (A0) {
      #pragma unroll
      for (int g = 0; g < 4; ++g)
        pf[g] = (float)pre0T[((size_t)e * FH_ + g * H_ + ub + cu) * 64 + rs + crow];
    }

    // ================= phase 1: layer0 on h0[e-1] =========================
    if (p == 0) {
      if (!DEEP && e >= 7) waitwide(f1p, (unsigned)(e - 6));  // ring-reuse guard
      if (e > 0) waitwide(f0p, (unsigned)e);
    }
    __syncthreads();

    const f16* h0s = ((e == 0) ? hinit : h0r + rt(e - 1) * BH_) + (size_t)rs * H_;
    f16x8 a0v[8], a1v[8];
    #pragma unroll
    for (int j = 0; j < 8; ++j) {
      const int k = (p * 8 + j) * 32 + lkq;
      if constexpr (DEEP) {
        a0v[j] = *(const f16x8*)(h0s + (size_t)lr * H_ + k);
        a1v[j] = *(const f16x8*)(h0s + (size_t)(16 + lr) * H_ + k);
      } else {
        a0v[j] = ld_b128_nc(h0s + (size_t)lr * H_ + k);
        a1v[j] = ld_b128_nc(h0s + (size_t)(16 + lr) * H_ + k);
      }
    }
    if (!DEEP) {
      asm volatile("s_waitcnt vmcnt(0)" ::: "memory");
      __builtin_amdgcn_sched_barrier(0);
    }

    float hn0 = 0.f, cn0 = 0.f;
    if (A0) {
      f32x4 acc0[2][2] = {};
      #pragma unroll
      for (int j = 0; j < 8; ++j)
        #pragma unroll
        for (int cf = 0; cf < 2; ++cf) {
          acc0[cf][0] = __builtin_amdgcn_mfma_f32_16x16x32_f16(a0v[j], l0w[cf][j], acc0[cf][0], 0, 0, 0);
          acc0[cf][1] = __builtin_amdgcn_mfma_f32_16x16x32_f16(a1v[j], l0w[cf][j], acc0[cf][1], 0, 0, 0);
        }
      #pragma unroll
      for (int cf = 0; cf < 2; ++cf)
        #pragma unroll
        for (int rf = 0; rf < 2; ++rf)
          #pragma unroll
          for (int ri = 0; ri < 4; ++ri)
            exc[0][p][rf * 16 + lrq + ri][cf * 16 + lr] = acc0[cf][rf][ri];
    }
    __syncthreads();   // B1

    if (A0) {
      float gv[4];
      #pragma unroll
      for (int g = 0; g < 4; ++g)
        gv[g] = exc[0][0][crow][g * 8 + cu] + exc[0][1][crow][g * 8 + cu]
              + exc[0][2][crow][g * 8 + cu] + exc[0][3][crow][g * 8 + cu] + pf[g];
      cn0 = sigf(gv[1]) * c0 + sigf(gv[0]) * tanhf_fast(gv[2]);
      hn0 = sigf(gv[3]) * tanhf_fast(cn0);
      c0 = cn0;
      smH[0][crow][cu] = (f16)hn0;
    }
    __syncthreads();   // B2

    if (A0 && p == 0) {
      const int row = lane >> 1, half = lane & 1;
      ull v = *(const ull*)&smH[0][row][half * 4];
      st_u64g((ull*)(h0r + rt(e) * BH_ + (size_t)(rs + row) * H_ + ub + half * 4), v);
      asm volatile("s_waitcnt vmcnt(0)" ::: "memory");
      if (lane == 0) st_u32g(&f0p[slot], (unsigned)(e + 1));
    }

    // ================= phase 2: layer1 step e-1 ===========================
    float hn1 = 0.f, cn1 = 0.f;
    if (A1) {
      if (p == 0 && e >= 2) waitwide(f1p, (unsigned)e);
      __syncthreads();

      const f16* h1s = ((e == 1) ? hinit + BH_ : h1r + rt(e - 2) * BH_) + (size_t)rs * H_;
      f16x8 c0v[8], c1v[8];
      #pragma unroll
      for (int j = 0; j < 8; ++j) {
        const int k = (p * 8 + j) * 32 + lkq;
        if constexpr (DEEP) {
          c0v[j] = *(const f16x8*)(h1s + (size_t)lr * H_ + k);
          c1v[j] = *(const f16x8*)(h1s + (size_t)(16 + lr) * H_ + k);
        } else {
          c0v[j] = ld_b128_nc(h1s + (size_t)lr * H_ + k);
          c1v[j] = ld_b128_nc(h1s + (size_t)(16 + lr) * H_ + k);
        }
      }

      // wih1 on still-live a-frags (overlaps h1 load latency)
      f32x4 acc1[2][2] = {};
      #pragma unroll
      for (int j = 0; j < 8; ++j)
        #pragma unroll
        for (int cf = 0; cf < 2; ++cf) {
          acc1[cf][0] = __builtin_amdgcn_mfma_f32_16x16x32_f16(a0v[j], l1aw[cf][j], acc1[cf][0], 0, 0, 0);
          acc1[cf][1] = __builtin_amdgcn_mfma_f32_16x16x32_f16(a1v[j], l1aw[cf][j], acc1[cf][1], 0, 0, 0);
        }
      if (!DEEP) {
        asm volatile("s_waitcnt vmcnt(0)" ::: "memory");
        __builtin_amdgcn_sched_barrier(0);
      }
      #pragma unroll
      for (int j = 0; j < 8; ++j)
        #pragma unroll
        for (int cf = 0; cf < 2; ++cf) {
          acc1[cf][0] = __builtin_amdgcn_mfma_f32_16x16x32_f16(c0v[j], l1bw[cf][j], acc1[cf][0], 0, 0, 0);
          acc1[cf][1] = __builtin_amdgcn_mfma_f32_16x16x32_f16(c1v[j], l1bw[cf][j], acc1[cf][1], 0, 0, 0);
        }

      #pragma unroll
      for (int cf = 0; cf < 2; ++cf)
        #pragma unroll
        for (int rf = 0; rf < 2; ++rf)
          #pragma unroll
          for (int ri = 0; ri < 4; ++ri)
            exc[1][p][rf * 16 + lrq + ri][cf * 16 + lr] = acc1[cf][rf][ri];
      __syncthreads();   // B3

      float gv[4];
      #pragma unroll
      for (int g = 0; g < 4; ++g)
        gv[g] = exc[1][0][crow][g * 8 + cu] + exc[1][1][crow][g * 8 + cu]
              + exc[1][2][crow][g * 8 + cu] + exc[1][3][crow][g * 8 + cu] + b1v[g];
      cn1 = sigf(gv[1]) * c1 + sigf(gv[0]) * tanhf_fast(gv[2]);
      hn1 = sigf(gv[3]) * tanhf_fast(cn1);
      c1 = cn1;
      smH[1][crow][cu] = (f16)hn1;
      __syncthreads();   // B4

      if (p == 1) {
        const int row = lane >> 1, half = lane & 1;
        ull v = *(const ull*)&smH[1][row][half * 4];
        st_u64g((ull*)(h1r + rt(e - 1) * BH_ + (size_t)(rs + row) * H_ + ub + half * 4), v);
        asm volatile("s_waitcnt vmcnt(0)" ::: "memory");
        if (lane == 0) st_u32g(&f1p[slot], (unsigned)(e + 1));
      }
    }

    // ---- off-critical-path cached outputs ----
    if (A0 && e == T_ - 1) { outh[cell] = hn0; outc[cell] = cn0; }
    if (A1) {
      out[(size_t)(rs + crow) * (T_ * H_) + (size_t)(e - 1) * H_ + ub + cu] = hn1;
      if (e == T_) { outh[BH_ + cell] = hn1; outc[BH_ + cell] = cn1; }
    }
  };

  body(BC<true>{}, BC<false>{}, 0);
  for (int e = 1; e < T_; ++e) body(BC<true>{}, BC<true>{}, e);
  body(BC<false>{}, BC<true>{}, T_);
}

// ---------------------------------------------------------------------------
extern "C" void kernel_launch(void* const* d_in, const int* in_sizes, int n_in,
                              void* d_out, int out_size, void* d_ws, size_t ws_size,
                              hipStream_t stream)
{
  const float* x    = (const float*)d_in[0];
  const float* h    = (const float*)d_in[1];
  const float* c    = (const float*)d_in[2];
  const float* Wih0 = (const float*)d_in[3];
  const float* Whh0 = (const float*)d_in[4];
  const float* bih0 = (const float*)d_in[5];
  const float* bhh0 = (const float*)d_in[6];
  const float* Wih1 = (const float*)d_in[7];
  const float* Whh1 = (const float*)d_in[8];
  const float* bih1 = (const float*)d_in[9];
  const float* bhh1 = (const float*)d_in[10];

  char* w = (char*)d_ws;
  size_t off = 0;
  auto carve = [&](size_t bytes) -> char* {
    char* ptr = w + off;
    off = (off + bytes + 255) & ~(size_t)255;
    return ptr;
  };
  f16*   pre0T = (f16*)  carve((size_t)T_ * B_ * FH_ * 2);
  f16*   xT    = (f16*)  carve((size_t)T_ * B_ * N_ * 2);
  f16*   wih0  = (f16*)  carve((size_t)FH_ * N_ * 2);
  f16*   whh0  = (f16*)  carve((size_t)FH_ * H_ * 2);
  f16*   wih1  = (f16*)  carve((size_t)FH_ * H_ * 2);
  f16*   whh1  = (f16*)  carve((size_t)FH_ * H_ * 2);
  float* bias0 = (float*)carve((size_t)FH_ * 4);
  float* bias1 = (float*)carve((size_t)FH_ * 4);
  f16*   hinit = (f16*)  carve((size_t)2 * BH_ * 2);
  f16*   h0s   = (f16*)  carve((size_t)8 * BH_ * 2);   // shallow fallback rings
  f16*   h1s   = (f16*)  carve((size_t)8 * BH_ * 2);
  unsigned* flags = (unsigned*)carve(512 * 4);
  const size_t base_end = off;
  f16*   h0ring = (f16*) carve((size_t)T_ * BH_ * 2);  // deep write-once rings
  f16*   h1ring = (f16*) carve((size_t)T_ * BH_ * 2);
  const bool deep = (off <= ws_size);
  if (base_end > ws_size) return;

  init_all<<<2048, 256, 0, stream>>>(x, h, Wih0, bih0, bhh0, Whh0, Wih1, Whh1, bih1, bhh1,
                                     xT, wih0, whh0, wih1, whh1, bias0, bias1, hinit, flags);
  gemm_pre0<<<4096, 256, 0, stream>>>(xT, wih0, bias0, pre0T);
  if (deep)
    lstm_seq<true><<<NWG_SEQ, 256, 0, stream>>>(pre0T, whh0, wih1, whh1, bias1, hinit,
                                                (const float*)c, h0ring, h1ring,
                                                (float*)d_out, flags);
  else
    lstm_seq<false><<<NWG_SEQ, 256, 0, stream>>>(pre0T, whh0, wih1, whh1, bias1, hinit,
                                                 (const float*)c, h0s, h1s,
                                                 (float*)d_out, flags);
}